// Round 3
// baseline (99.969 us; speedup 1.0000x reference)
//
#include <hip/hip_runtime.h>
#include <math.h>

#define BLOCK 256
#define PPT 8               // rows per thread -> 2048 rows per block
#define RPB (BLOCK * PPT)   // 2048
#define CLEN 32             // cols per block tile
#define SPAD 257            // scmin padded stride (bank = (c+i)%32, conflict-free)

typedef float f32x2 __attribute__((ext_vector_type(2)));

__device__ __forceinline__ float min3f(float a, float b, float c) {
    return fminf(fminf(a, b), c);   // -> v_min3_f32
}
__device__ __forceinline__ f32x2 pkfma(f32x2 a, f32x2 b, f32x2 c) {
    return __builtin_elementwise_fma(a, b, c);   // -> v_pk_fma_f32
}

// ROUND-2 STRUCTURE, single change: global atomicMin -> private partial
// stores (min is associative; finalize reduces across blocks). No RMW
// contention at the coherence point, no 0xFF memset dispatch, no key
// encode/decode. Partial layouts (disjoint per block, written before read):
//   rpart[cb][b*N + r]  : this block's min over its 32 cols, per row
//   cpart[rb][b*M + c]  : this block's min over its 2048 rows, per col
__global__ __launch_bounds__(BLOCK, 4) void chamfer_tile_kernel(
    const float* __restrict__ arr1, const float* __restrict__ arr2,
    int N, int M, int BN, int BM,
    float* __restrict__ rpart, float* __restrict__ cpart,
    float* __restrict__ out)
{
    const int b  = blockIdx.z;
    const int r0 = blockIdx.x * RPB;     // row offset within batch
    const int c0 = blockIdx.y * CLEN;    // col offset within batch

    // Zero the output accumulator exactly once (finalize is a later dispatch).
    if (blockIdx.x == 0 && blockIdx.y == 0 && b == 0 && threadIdx.x == 0)
        out[0] = 0.0f;

    // SoA col staging: packed pairs load as single ds_read_b64 (uniform addr).
    __shared__ __align__(16) float sbx[CLEN], sby[CLEN], sbz[CLEN], sbw[CLEN];
    __shared__ float scmin[CLEN][SPAD];
    __shared__ float cred[8][CLEN];

    // Stage col points, prescaled: (-2x, -2y, -2z) and |b|^2.
    if (threadIdx.x < CLEN) {
        const float* p = arr2 + ((size_t)b * M + c0 + threadIdx.x) * 3;
        float x = p[0], y = p[1], z = p[2];
        sbx[threadIdx.x] = -2.0f * x;
        sby[threadIdx.x] = -2.0f * y;
        sbz[threadIdx.x] = -2.0f * z;
        sbw[threadIdx.x] = __builtin_fmaf(x, x, __builtin_fmaf(y, y, z * z));
    }
    __syncthreads();

    // Row points in registers (+ their squared norms)
    float ax[PPT], ay[PPT], az[PPT], a2[PPT], mn[PPT];
    const float* abase = arr1 + ((size_t)b * N + r0) * 3;
#pragma unroll
    for (int k = 0; k < PPT; ++k) {
        int idx = threadIdx.x + k * BLOCK;
        float x = abase[idx * 3 + 0];
        float y = abase[idx * 3 + 1];
        float z = abase[idx * 3 + 2];
        ax[k] = x; ay[k] = y; az[k] = z;
        a2[k] = __builtin_fmaf(x, x, __builtin_fmaf(y, y, z * z));
        mn[k] = __builtin_inff();
    }

    // Inner scan: 2 cols per f32x2, rows in pairs, fully unrolled.
#pragma unroll
    for (int jj = 0; jj < CLEN; jj += 2) {
        f32x2 bx = *(const f32x2*)&sbx[jj];
        f32x2 by = *(const f32x2*)&sby[jj];
        f32x2 bz = *(const f32x2*)&sbz[jj];
        f32x2 bw = *(const f32x2*)&sbw[jj];
        float cx, cy;                      // col-fold accumulators (2 cols)
#pragma unroll
        for (int k = 0; k < PPT; k += 2) {
            f32x2 t0 = bw + (f32x2){a2[k],     a2[k]};
            f32x2 t1 = bw + (f32x2){a2[k + 1], a2[k + 1]};
            f32x2 d0 = pkfma(bx, (f32x2){ax[k], ax[k]},
                       pkfma(by, (f32x2){ay[k], ay[k]},
                       pkfma(bz, (f32x2){az[k], az[k]}, t0)));
            f32x2 d1 = pkfma(bx, (f32x2){ax[k + 1], ax[k + 1]},
                       pkfma(by, (f32x2){ay[k + 1], ay[k + 1]},
                       pkfma(bz, (f32x2){az[k + 1], az[k + 1]}, t1)));
            mn[k]     = min3f(mn[k],     d0.x, d0.y);   // row mins
            mn[k + 1] = min3f(mn[k + 1], d1.x, d1.y);
            if (k == 0) {                               // col fold seed
                cx = fminf(d0.x, d1.x);
                cy = fminf(d0.y, d1.y);
            } else {                                    // col fold: min3
                cx = min3f(cx, d0.x, d1.x);
                cy = min3f(cy, d0.y, d1.y);
            }
        }
        scmin[jj][threadIdx.x]     = cx;   // bank (jj+tid)%32: 2-way max, free
        scmin[jj + 1][threadIdx.x] = cy;
    }

    // Row partials -> plain coalesced stores (disjoint region per col-block)
    float* rp = rpart + (size_t)blockIdx.y * BN + (size_t)b * N + r0;
#pragma unroll
    for (int k = 0; k < PPT; ++k)
        rp[threadIdx.x + k * BLOCK] = mn[k];

    __syncthreads();

    // Col reduce stage 1: thread (c = tid&31, s = tid>>5) tree-reduces
    // scmin[c][s*32 .. s*32+31].  bank = (c+i)%32 -> <=2-way (free).
    {
        int c = threadIdx.x & 31, s = threadIdx.x >> 5;
        const float* row = &scmin[c][s * 32];
        float v0 = row[0], v1 = row[1];
#pragma unroll
        for (int i = 2; i < 32; i += 2) {
            v0 = fminf(v0, row[i]);
            v1 = fminf(v1, row[i + 1]);
        }
        cred[s][c] = fminf(v0, v1);
    }
    __syncthreads();
    // Stage 2: 32 threads fold the 8 segment partials, plain store per col.
    if (threadIdx.x < CLEN) {
        float v = fminf(min3f(min3f(min3f(cred[0][threadIdx.x],
                                          cred[1][threadIdx.x],
                                          cred[2][threadIdx.x]),
                                    cred[3][threadIdx.x],
                                    cred[4][threadIdx.x]),
                              cred[5][threadIdx.x],
                              cred[6][threadIdx.x]),
                        cred[7][threadIdx.x]);
        cpart[(size_t)blockIdx.x * BM + (size_t)b * M + c0 + threadIdx.x] = v;
    }
}

// Finalize: cross-block min-reduce of the partials + weighted sum.
//   rows: 2 threads per row, each folds 128 of the 256 col-block partials
//         (8 independent load chains -> ~16 loads in flight), shfl_xor merge.
//   cols: 1 thread per col folds the 4 row-block partials.
// All loads wave-coalesced (lane-consecutive rows/cols at fixed cb/rb).
__global__ __launch_bounds__(256) void chamfer_finalize_kernel(
    const float* __restrict__ rpart, const float* __restrict__ cpart,
    int BN, int BM, int ncb, int nrb, float* __restrict__ out)
{
    const float wA = 1.0f / (float)BN;
    const float wB = 1.0f / (float)BM;
    const int gid = blockIdx.x * 256 + threadIdx.x;

    float s = 0.0f;

    // ---- rows: gid -> (row i = gid>>1, half q = gid&1) ----
    {
        const int i = gid >> 1, q = gid & 1;
        if (i < BN) {
            const int half = ncb >> 1;                 // 128
            const float* bp = rpart + (size_t)q * half * BN + i;
            float v0 = bp[(size_t)0 * BN], v1 = bp[(size_t)1 * BN];
            float v2 = bp[(size_t)2 * BN], v3 = bp[(size_t)3 * BN];
            float v4 = bp[(size_t)4 * BN], v5 = bp[(size_t)5 * BN];
            float v6 = bp[(size_t)6 * BN], v7 = bp[(size_t)7 * BN];
            for (int c = 8; c < half; c += 8) {
                const float* p = bp + (size_t)c * BN;
                v0 = fminf(v0, p[(size_t)0 * BN]);
                v1 = fminf(v1, p[(size_t)1 * BN]);
                v2 = fminf(v2, p[(size_t)2 * BN]);
                v3 = fminf(v3, p[(size_t)3 * BN]);
                v4 = fminf(v4, p[(size_t)4 * BN]);
                v5 = fminf(v5, p[(size_t)5 * BN]);
                v6 = fminf(v6, p[(size_t)6 * BN]);
                v7 = fminf(v7, p[(size_t)7 * BN]);
            }
            float m = fminf(min3f(min3f(v0, v1, v2), v3, v4), min3f(v5, v6, v7));
            float om = __shfl_xor(m, 1, 64);           // partner has other half
            m = fminf(m, om);
            if (q == 0) s += wA * m;
        }
    }

    // ---- cols: gid -> col (first BM threads) ----
    if (gid < BM) {
        const float* cp = cpart + gid;
        float m = cp[0];
        for (int rb = 1; rb < nrb; ++rb)
            m = fminf(m, cp[(size_t)rb * BM]);
        s += wB * m;
    }

#pragma unroll
    for (int off = 32; off > 0; off >>= 1)
        s += __shfl_down(s, off, 64);

    __shared__ float wsum[4];
    int lane = threadIdx.x & 63, wv = threadIdx.x >> 6;
    if (lane == 0) wsum[wv] = s;
    __syncthreads();
    if (threadIdx.x == 0)
        atomicAdd(out, wsum[0] + wsum[1] + wsum[2] + wsum[3]);
}

extern "C" void kernel_launch(void* const* d_in, const int* in_sizes, int n_in,
                              void* d_out, int out_size, void* d_ws, size_t ws_size,
                              hipStream_t stream)
{
    const float* arr1 = (const float*)d_in[0];
    const float* arr2 = (const float*)d_in[1];
    float* out = (float*)d_out;

    const int Bb = 4;
    const int N = in_sizes[0] / (Bb * 3);   // 8192
    const int M = in_sizes[1] / (Bb * 3);   // 8192
    const int BN = Bb * N, BM = Bb * M;
    const int ncb = M / CLEN;               // 256 col-blocks per batch
    const int nrb = N / RPB;                // 4   row-blocks per batch

    float* rpart = (float*)d_ws;                       // [ncb][BN]  33.5 MB
    float* cpart = rpart + (size_t)ncb * BN;           // [nrb][BM]   0.5 MB
    // No memset needed: every partial is written by the tile kernel before
    // the finalize kernel reads it (workspace poison is fully overwritten).

    dim3 grid(N / RPB, M / CLEN, Bb);       // (4, 256, 4) = 4096 blocks
    chamfer_tile_kernel<<<grid, BLOCK, 0, stream>>>(arr1, arr2, N, M, BN, BM,
                                                    rpart, cpart, out);

    const int fblocks = (2 * BN + 255) / 256;          // 256 blocks
    chamfer_finalize_kernel<<<fblocks, 256, 0, stream>>>(rpart, cpart,
                                                         BN, BM, ncb, nrb, out);
}